// Round 3
// baseline (24395.320 us; speedup 1.0000x reference)
//
#include <hip/hip_runtime.h>
#include <hip/hip_bf16.h>
#include <cstdint>
#include <cstddef>

// ---------------------------------------------------------------------------
// 2-layer GRU decoder, persistent-kernel version.
// B=8192, H=512, ENC=1024, ATOM=64, 49 steps.
// One kernel runs all 49 steps; phases separated by a 2-level device-scope
// grid barrier (one-shot counter slots, zeroed by zerok every launch).
// Gate-permuted weights: q = 48*(j/16) + 16*g + (j%16) <-> orig row g*512+j.
// ---------------------------------------------------------------------------

typedef __attribute__((ext_vector_type(8))) __bf16 bf16x8;
typedef __attribute__((ext_vector_type(4))) __bf16 bf16x4;
typedef __attribute__((ext_vector_type(4))) float f32x4;

#define B_ROWS 8192
#define HID 512
#define GATE3 1536
#define ATOM 64
#define NSTEP 49
#define NBLK 1024
#define NBAR 200
#define NBARINTS (NBAR * 1024 + NBAR * 32)

#define GLOAD_LDS16(gp, sp)                                                   \
  __builtin_amdgcn_global_load_lds(                                           \
      (__attribute__((address_space(1))) void*)(gp),                          \
      (__attribute__((address_space(3))) void*)(sp), 16, 0, 0)

__device__ inline float sig_(float x) { return 1.f / (1.f + __expf(-x)); }
__device__ inline float tanh_(float x) { return 2.f / (1.f + __expf(-2.f * x)) - 1.f; }

// ---------------------------------------------------------------------------
// 2-level grid barrier. bar1: per-barrier 32 group counters (128B apart).
// bar2: per-barrier final counter. Slots are single-use (bid indexes them).
// ---------------------------------------------------------------------------
__device__ __forceinline__ void gridbar(int* bar1, int* bar2, int bid, int blk)
{
    __syncthreads();
    if (threadIdx.x == 0) {
        __threadfence();   // agent-scope release: writes visible device-wide
        int* c1 = bar1 + bid * 1024 + (blk >> 5) * 32;
        const int prev = __hip_atomic_fetch_add(c1, 1, __ATOMIC_ACQ_REL,
                                                __HIP_MEMORY_SCOPE_AGENT);
        int* c2 = bar2 + bid * 32;
        if (prev == 31)
            __hip_atomic_fetch_add(c2, 1, __ATOMIC_ACQ_REL,
                                   __HIP_MEMORY_SCOPE_AGENT);
        while (__hip_atomic_load(c2, __ATOMIC_RELAXED,
                                 __HIP_MEMORY_SCOPE_AGENT) < 32)
            __builtin_amdgcn_s_sleep(1);
        __threadfence();   // agent-scope acquire: invalidate stale caches
    }
    __syncthreads();
}

// ---------------------------------------------------------------------------
// Core tile GEMM: acc += A[m0..+64) @ Bp[n0..+192)^T, K=512, BK=32.
// 4 waves: wave w owns 48-col triple (w*48) within the 192-col strip.
// ---------------------------------------------------------------------------
__device__ __forceinline__ void gru_mm(
    const __bf16* __restrict__ A, const __bf16* __restrict__ Bp,
    int m0, int n0, int tid, __bf16* As, __bf16* Bs, f32x4 (&acc)[4][3])
{
    const int lane = tid & 63, w = tid >> 6;
    const int u = lane & 15, koff = (lane >> 4) * 8;
    const __bf16* Ap  = A  + (size_t)(m0 + (tid >> 2)) * HID + (tid & 3) * 8;
    const __bf16* Bg0 = Bp + (size_t)(n0 + (tid >> 2)) * HID + (tid & 3) * 8;
    const __bf16* Bg1 = Bg0 + (size_t)64  * HID;
    const __bf16* Bg2 = Bg0 + (size_t)128 * HID;
    __bf16* AsW  = As + w * 512;
    __bf16* BsW0 = Bs + w * 512;
    __bf16* BsW1 = Bs + 2048 + w * 512;
    __bf16* BsW2 = Bs + 4096 + w * 512;

    for (int kt = 0; kt < HID / 32; ++kt) {
        __syncthreads();
        GLOAD_LDS16(Ap,  AsW);
        GLOAD_LDS16(Bg0, BsW0);
        GLOAD_LDS16(Bg1, BsW1);
        GLOAD_LDS16(Bg2, BsW2);
        Ap += 32; Bg0 += 32; Bg1 += 32; Bg2 += 32;
        __syncthreads();

        bf16x8 af[4], bfr[3];
        #pragma unroll
        for (int mf = 0; mf < 4; ++mf)
            af[mf] = *(const bf16x8*)&As[(mf * 16 + u) * 32 + koff];
        #pragma unroll
        for (int g = 0; g < 3; ++g)
            bfr[g] = *(const bf16x8*)&Bs[(w * 48 + g * 16 + u) * 32 + koff];
        #pragma unroll
        for (int mf = 0; mf < 4; ++mf)
            #pragma unroll
            for (int g = 0; g < 3; ++g)
                acc[mf][g] = __builtin_amdgcn_mfma_f32_16x16x32_bf16(
                    af[mf], bfr[g], acc[mf][g], 0, 0, 0);
    }
}

// ---------------------------------------------------------------------------
// Persistent decode loop. 1024 blocks x 256 threads, 4 blocks/CU.
// ---------------------------------------------------------------------------
__global__ __launch_bounds__(256, 4) void decode_loop(
    const __bf16* __restrict__ whh0p, const __bf16* __restrict__ wih1p,
    const __bf16* __restrict__ whh1p, const __bf16* __restrict__ woutb,
    const float* __restrict__ G0p, const float* __restrict__ bhh0p,
    const float* __restrict__ bih1p, const float* __restrict__ bhh1p,
    const float* __restrict__ bout,
    float* h0fA, __bf16* h0bA, float* h1fA, __bf16* h1bA,
    float* h0fB, __bf16* h0bB, float* h1fB, __bf16* h1bB,
    __bf16* gi1, int* p, float* yout, int* bar1, int* bar2)
{
    __shared__ __bf16 As[64 * 32];    // 4 KB
    __shared__ __bf16 Bs[192 * 32];   // 12 KB

    const int blk = blockIdx.x, tid = threadIdx.x;
    const int lane = tid & 63, w = tid >> 6, u = lane & 15;
    const int koff = (lane >> 4) * 8;
    const int m0 = (blk >> 3) * 64;       // 128 row-tiles x 8 col-strips
    const int n0 = (blk & 7) * 192;
    const int t  = (blk & 7) * 4 + w;     // triple index 0..31
    const int j  = t * 16 + u;            // h-unit this lane owns
    const int qb = t * 48 + u;            // permuted gate base col
    const int rbase = m0 + ((lane >> 4) << 2);
    int bid = 0;

    const float bhr0 = bhh0p[qb], bhz0 = bhh0p[qb + 16], bhn0 = bhh0p[qb + 32];
    const float bir1 = bih1p[qb], biz1 = bih1p[qb + 16], bin1 = bih1p[qb + 32];
    const float bhr1 = bhh1p[qb], bhz1 = bhh1p[qb + 16], bhn1 = bhh1p[qb + 32];
    float boutv[4];
    #pragma unroll
    for (int nf = 0; nf < 4; ++nf) boutv[nf] = bout[nf * 16 + u];

    #pragma unroll 1
    for (int step = 0; step < NSTEP; ++step) {
        const bool even = (step & 1) == 0;
        const float*  h0f_c = even ? h0fA : h0fB;
        float*        h0f_n = even ? h0fB : h0fA;
        const __bf16* h0b_c = even ? h0bA : h0bB;
        __bf16*       h0b_n = even ? h0bB : h0bA;
        const float*  h1f_c = even ? h1fA : h1fB;
        float*        h1f_n = even ? h1fB : h1fA;
        const __bf16* h1b_c = even ? h1bA : h1bB;
        __bf16*       h1b_n = even ? h1bB : h1bA;

        // ---- phase A: GRU0 (gh0 GEMM + gate update; gi from G0p[p]) ----
        {
            f32x4 acc[4][3] = {};
            gru_mm(h0b_c, whh0p, m0, n0, tid, As, Bs, acc);
            #pragma unroll
            for (int mf = 0; mf < 4; ++mf)
                #pragma unroll
                for (int r = 0; r < 4; ++r) {
                    const int row = rbase + mf * 16 + r;
                    const float* g0 = G0p + (size_t)p[row] * GATE3 + qb;
                    const float rr = sig_(g0[0]  + acc[mf][0][r] + bhr0);
                    const float zz = sig_(g0[16] + acc[mf][1][r] + bhz0);
                    const float nn = tanh_(g0[32] + rr * (acc[mf][2][r] + bhn0));
                    const float hp = h0f_c[(size_t)row * HID + j];
                    const float hv = (1.f - zz) * nn + zz * hp;
                    h0f_n[(size_t)row * HID + j] = hv;
                    h0b_n[(size_t)row * HID + j] = (__bf16)hv;
                }
        }
        gridbar(bar1, bar2, bid++, blk);

        // ---- phase B1: gi1 = h0_new @ wih1p^T (bf16 store, permuted) ----
        {
            f32x4 acc[4][3] = {};
            gru_mm(h0b_n, wih1p, m0, n0, tid, As, Bs, acc);
            #pragma unroll
            for (int mf = 0; mf < 4; ++mf)
                #pragma unroll
                for (int r = 0; r < 4; ++r) {
                    const int row = rbase + mf * 16 + r;
                    #pragma unroll
                    for (int g = 0; g < 3; ++g)
                        gi1[(size_t)row * GATE3 + qb + g * 16] =
                            (__bf16)acc[mf][g][r];
                }
        }
        gridbar(bar1, bar2, bid++, blk);

        // ---- phase B2: GRU1 (gh1 GEMM + gate update; gi from gi1) ----
        {
            f32x4 acc[4][3] = {};
            gru_mm(h1b_c, whh1p, m0, n0, tid, As, Bs, acc);
            #pragma unroll
            for (int mf = 0; mf < 4; ++mf)
                #pragma unroll
                for (int r = 0; r < 4; ++r) {
                    const int row = rbase + mf * 16 + r;
                    const __bf16* gi = gi1 + (size_t)row * GATE3 + qb;
                    const float rr = sig_((float)gi[0]  + bir1 + acc[mf][0][r] + bhr1);
                    const float zz = sig_((float)gi[16] + biz1 + acc[mf][1][r] + bhz1);
                    const float nn = tanh_((float)gi[32] + bin1 +
                                           rr * (acc[mf][2][r] + bhn1));
                    const float hp = h1f_c[(size_t)row * HID + j];
                    const float hv = (1.f - zz) * nn + zz * hp;
                    h1f_n[(size_t)row * HID + j] = hv;
                    h1b_n[(size_t)row * HID + j] = (__bf16)hv;
                }
        }
        gridbar(bar1, bar2, bid++, blk);

        // ---- phase C: logits + log_softmax + argmax (blocks 0..127) ----
        if (blk < 128) {
            const int m0c = blk * 64;
            f32x4 acc[4] = {};
            const __bf16* Ap = h1b_n + (size_t)(m0c + (tid >> 2)) * HID + (tid & 3) * 8;
            const __bf16* Wp = woutb + (size_t)(tid >> 2) * HID + (tid & 3) * 8;
            __bf16* AsW = As + w * 512;
            __bf16* BsW = Bs + w * 512;
            for (int kt = 0; kt < HID / 32; ++kt) {
                __syncthreads();
                GLOAD_LDS16(Ap, AsW);
                GLOAD_LDS16(Wp, BsW);
                Ap += 32; Wp += 32;
                __syncthreads();
                const bf16x8 af = *(const bf16x8*)&As[(w * 16 + u) * 32 + koff];
                #pragma unroll
                for (int nf = 0; nf < 4; ++nf) {
                    const bf16x8 bfr = *(const bf16x8*)&Bs[(nf * 16 + u) * 32 + koff];
                    acc[nf] = __builtin_amdgcn_mfma_f32_16x16x32_bf16(
                        af, bfr, acc[nf], 0, 0, 0);
                }
            }
            float* yS = yout + (size_t)step * B_ROWS * ATOM;
            #pragma unroll
            for (int r = 0; r < 4; ++r) {
                const int row = m0c + w * 16 + ((lane >> 4) << 2) + r;
                float l[4];
                #pragma unroll
                for (int nf = 0; nf < 4; ++nf) l[nf] = acc[nf][r] + boutv[nf];

                float mv = l[0]; int mi = u;
                #pragma unroll
                for (int nf = 1; nf < 4; ++nf)
                    if (l[nf] > mv) { mv = l[nf]; mi = nf * 16 + u; }
                #pragma unroll
                for (int off = 1; off <= 8; off <<= 1) {
                    const float ov = __shfl_xor(mv, off, 64);
                    const int   oi = __shfl_xor(mi, off, 64);
                    if (ov > mv || (ov == mv && oi < mi)) { mv = ov; mi = oi; }
                }
                float se = 0.f;
                #pragma unroll
                for (int nf = 0; nf < 4; ++nf) se += __expf(l[nf] - mv);
                #pragma unroll
                for (int off = 1; off <= 8; off <<= 1) se += __shfl_xor(se, off, 64);
                const float lse = logf(se);

                #pragma unroll
                for (int nf = 0; nf < 4; ++nf)
                    yS[(size_t)row * ATOM + nf * 16 + u] = l[nf] - mv - lse;
                if (u == 0) p[row] = mi;
            }
        }
        gridbar(bar1, bar2, bid++, blk);
    }
}

// ---------------------------------------------------------------------------
// Init GEMM (enc -> h): BM=BN=128, BK=32, tanh epilogue splitting h0|h1.
// ---------------------------------------------------------------------------
__global__ __launch_bounds__(256) void gemm_init(
    const __bf16* __restrict__ A, const __bf16* __restrict__ B,
    int N, int K, const float* __restrict__ bias,
    float* __restrict__ H0f, __bf16* __restrict__ H0b,
    float* __restrict__ H1f, __bf16* __restrict__ H1b)
{
    __shared__ __bf16 As[128 * 32];
    __shared__ __bf16 Bs[128 * 32];

    const int tid  = threadIdx.x;
    const int lane = tid & 63;
    const int w    = tid >> 6;
    const int wm   = w >> 1, wn = w & 1;
    const int m0   = blockIdx.x * 128;
    const int n0   = blockIdx.y * 128;

    f32x4 acc[4][4] = {};

    const int i0 = w * 64 + lane;
    const int i1 = i0 + 256;
    const __bf16* Ap0 = A + (size_t)(m0 + (i0 >> 2)) * K + (i0 & 3) * 8;
    const __bf16* Ap1 = A + (size_t)(m0 + (i1 >> 2)) * K + (i1 & 3) * 8;
    const __bf16* Bp0 = B + (size_t)(n0 + (i0 >> 2)) * K + (i0 & 3) * 8;
    const __bf16* Bp1 = B + (size_t)(n0 + (i1 >> 2)) * K + (i1 & 3) * 8;
    __bf16* As0 = As + w * 512;
    __bf16* As1 = As + 2048 + w * 512;
    __bf16* Bs0 = Bs + w * 512;
    __bf16* Bs1 = Bs + 2048 + w * 512;

    const int mrow = wm * 64 + (lane & 15);
    const int nrow = wn * 64 + (lane & 15);
    const int koff = (lane >> 4) * 8;

    for (int kt = 0; kt < K / 32; ++kt) {
        __syncthreads();
        GLOAD_LDS16(Ap0, As0);
        GLOAD_LDS16(Ap1, As1);
        GLOAD_LDS16(Bp0, Bs0);
        GLOAD_LDS16(Bp1, Bs1);
        Ap0 += 32; Ap1 += 32; Bp0 += 32; Bp1 += 32;
        __syncthreads();

        bf16x8 af[4], bfr[4];
        #pragma unroll
        for (int f = 0; f < 4; ++f) {
            af[f]  = *(const bf16x8*)&As[(mrow + f * 16) * 32 + koff];
            bfr[f] = *(const bf16x8*)&Bs[(nrow + f * 16) * 32 + koff];
        }
        #pragma unroll
        for (int mf = 0; mf < 4; ++mf)
            #pragma unroll
            for (int nf = 0; nf < 4; ++nf)
                acc[mf][nf] = __builtin_amdgcn_mfma_f32_16x16x32_bf16(
                    af[mf], bfr[nf], acc[mf][nf], 0, 0, 0);
    }

    const int colb = n0 + wn * 64 + (lane & 15);
    const int rowb = m0 + wm * 64 + ((lane >> 4) << 2);
    #pragma unroll
    for (int mf = 0; mf < 4; ++mf)
        #pragma unroll
        for (int nf = 0; nf < 4; ++nf) {
            const int col = colb + nf * 16;
            #pragma unroll
            for (int r = 0; r < 4; ++r) {
                const int row = rowb + mf * 16 + r;
                const float v = tanhf(acc[mf][nf][r] + bias[col]);
                if (col < HID) {
                    H0f[(size_t)row * HID + col] = v;
                    H0b[(size_t)row * HID + col] = (__bf16)v;
                } else {
                    H1f[(size_t)row * HID + col - HID] = v;
                    H1b[(size_t)row * HID + col - HID] = (__bf16)v;
                }
            }
        }
}

// ---------------------------------------------------------------------------
// prep kernels
// ---------------------------------------------------------------------------
__device__ inline int permQ(int q) {          // permuted q -> original row
    const int t = q / 48, rem = q % 48;
    return (rem / 16) * HID + t * 16 + (rem % 16);
}

__global__ __launch_bounds__(256) void f2b(const float* __restrict__ s,
                                           __bf16* __restrict__ d, int n)
{
    const int i = (blockIdx.x * 256 + threadIdx.x) * 4;
    if (i + 3 < n) {
        const float4 v = *(const float4*)(s + i);
        bf16x4 o = { (__bf16)v.x, (__bf16)v.y, (__bf16)v.z, (__bf16)v.w };
        *(bf16x4*)(d + i) = o;
    }
}

__global__ __launch_bounds__(256) void f2bp(const float* __restrict__ s,
                                            __bf16* __restrict__ d)
{
    const int idx = blockIdx.x * 256 + threadIdx.x;   // 1536*128
    const int q = idx >> 7, k = (idx & 127) << 2;
    const int o = permQ(q);
    const float4 v = *(const float4*)(s + (size_t)o * HID + k);
    bf16x4 ov = { (__bf16)v.x, (__bf16)v.y, (__bf16)v.z, (__bf16)v.w };
    *(bf16x4*)(d + (size_t)q * HID + k) = ov;
}

__global__ __launch_bounds__(256) void bperm(const float* __restrict__ s,
                                             float* __restrict__ d)
{
    const int q = blockIdx.x * 256 + threadIdx.x;
    if (q < GATE3) d[q] = s[permQ(q)];
}

__global__ __launch_bounds__(256) void g0pk(const float* __restrict__ emb,
                                            const float* __restrict__ wih0,
                                            const float* __restrict__ bih0,
                                            float* __restrict__ G0p)
{
    const int i = blockIdx.x * 256 + threadIdx.x;   // 64*1536
    if (i >= ATOM * GATE3) return;
    const int a = i / GATE3, q = i % GATE3;
    const int o = permQ(q);
    float s = bih0[o];
    for (int k = 0; k < 50; ++k) s += emb[a * 50 + k] * wih0[o * 50 + k];
    G0p[i] = s;
}

__global__ __launch_bounds__(256) void initp(int* __restrict__ p)
{
    const int i = blockIdx.x * 256 + threadIdx.x;
    if (i < B_ROWS) p[i] = 1;   // SOS
}

__global__ __launch_bounds__(256) void zerok(int* __restrict__ a, int n)
{
    const int i = blockIdx.x * 256 + threadIdx.x;
    if (i < n) a[i] = 0;
}

// ---------------------------------------------------------------------------
extern "C" void kernel_launch(void* const* d_in, const int* in_sizes, int n_in,
                              void* d_out, int out_size, void* d_ws, size_t ws_size,
                              hipStream_t stream)
{
    (void)in_sizes; (void)n_in; (void)out_size; (void)ws_size;
    const float* enc   = (const float*)d_in[0];
    const float* emb   = (const float*)d_in[1];
    const float* w_h0  = (const float*)d_in[2];
    const float* b_h0  = (const float*)d_in[3];
    const float* w_ih0 = (const float*)d_in[4];
    const float* w_hh0 = (const float*)d_in[5];
    const float* b_hh0 = (const float*)d_in[7];
    const float* b_ih0 = (const float*)d_in[6];
    const float* w_ih1 = (const float*)d_in[8];
    const float* w_hh1 = (const float*)d_in[9];
    const float* b_ih1 = (const float*)d_in[10];
    const float* b_hh1 = (const float*)d_in[11];
    const float* w_out = (const float*)d_in[12];
    const float* b_out = (const float*)d_in[13];
    float* out = (float*)d_out;

    char* ws = (char*)d_ws;
    size_t off = 0;
    auto alloc = [&](size_t bytes) -> void* {
        void* pp = ws + off;
        off = (off + bytes + 255) & ~(size_t)255;
        return pp;
    };
    __bf16* whh0p = (__bf16*)alloc((size_t)GATE3 * HID * 2);
    __bf16* wih1p = (__bf16*)alloc((size_t)GATE3 * HID * 2);
    __bf16* whh1p = (__bf16*)alloc((size_t)GATE3 * HID * 2);
    __bf16* woutb = (__bf16*)alloc((size_t)ATOM * HID * 2);
    float*  G0p   = (float*) alloc((size_t)ATOM * GATE3 * 4);
    float*  bhh0p = (float*) alloc(GATE3 * 4);
    float*  bih1p = (float*) alloc(GATE3 * 4);
    float*  bhh1p = (float*) alloc(GATE3 * 4);
    float*  h0f[2]; __bf16* h0b[2]; float* h1f[2]; __bf16* h1b[2];
    for (int i = 0; i < 2; ++i) {
        h0f[i] = (float*) alloc((size_t)B_ROWS * HID * 4);
        h0b[i] = (__bf16*)alloc((size_t)B_ROWS * HID * 2);
        h1f[i] = (float*) alloc((size_t)B_ROWS * HID * 4);
        h1b[i] = (__bf16*)alloc((size_t)B_ROWS * HID * 2);
    }
    int* p    = (int*)alloc((size_t)B_ROWS * 4);
    int* bar1 = (int*)alloc((size_t)NBAR * 1024 * 4);
    int* bar2 = (int*)alloc((size_t)NBAR * 32 * 4);
    const size_t mark = off;
    __bf16* gi1   = (__bf16*)alloc((size_t)B_ROWS * GATE3 * 2);   // loop-only
    const size_t endA = off;
    off = mark;                        // init-only buffers alias gi1
    __bf16* enc_b = (__bf16*)alloc((size_t)B_ROWS * 1024 * 2);
    __bf16* wh0b  = (__bf16*)alloc((size_t)1024 * 1024 * 2);
    if (off < endA) off = endA;

    // ---- prep ----
    zerok<<<(NBARINTS + 255) / 256, 256, 0, stream>>>(bar1, NBARINTS);
    f2b <<<8192, 256, 0, stream>>>(enc,  enc_b, B_ROWS * 1024);
    f2b <<<1024, 256, 0, stream>>>(w_h0, wh0b,  1024 * 1024);
    f2b <<<32,   256, 0, stream>>>(w_out, woutb, ATOM * HID);
    f2bp<<<768,  256, 0, stream>>>(w_hh0, whh0p);
    f2bp<<<768,  256, 0, stream>>>(w_ih1, wih1p);
    f2bp<<<768,  256, 0, stream>>>(w_hh1, whh1p);
    bperm<<<6, 256, 0, stream>>>(b_hh0, bhh0p);
    bperm<<<6, 256, 0, stream>>>(b_ih1, bih1p);
    bperm<<<6, 256, 0, stream>>>(b_hh1, bhh1p);
    g0pk<<<384, 256, 0, stream>>>(emb, w_ih0, b_ih0, G0p);
    initp<<<32, 256, 0, stream>>>(p);

    gemm_init<<<dim3(B_ROWS / 128, 1024 / 128), 256, 0, stream>>>(
        enc_b, wh0b, 1024, 1024, b_h0, h0f[0], h0b[0], h1f[0], h1b[0]);

    // ---- persistent 49-step loop ----
    decode_loop<<<NBLK, 256, 0, stream>>>(
        whh0p, wih1p, whh1p, woutb, G0p, bhh0p, bih1p, bhh1p, b_out,
        h0f[0], h0b[0], h1f[0], h1b[0],
        h0f[1], h0b[1], h1f[1], h1b[1],
        gi1, p, out, bar1, bar2);
}

// Round 4
// 9553.568 us; speedup vs baseline: 2.5535x; 2.5535x over previous
//
#include <hip/hip_runtime.h>
#include <hip/hip_bf16.h>
#include <cstdint>
#include <cstddef>

// ---------------------------------------------------------------------------
// 2-layer GRU decoder. B=8192, H=512, ENC=1024, ATOM=64, 49 steps.
// 3 kernels/step: GRU0 (gemm+gate), dual-GEMM GRU1 (gi1+gh1+gate), out.
// Step GEMMs load MFMA fragments DIRECTLY from global (no LDS, no barriers):
// fragment = 16B contiguous per lane at row*512 + kt*32 + (lane>>4)*8.
// Gate-permuted weights: q = 48*(j/16) + 16*g + (j%16) <-> orig row g*512+j.
// ---------------------------------------------------------------------------

typedef __attribute__((ext_vector_type(8))) __bf16 bf16x8;
typedef __attribute__((ext_vector_type(4))) __bf16 bf16x4;
typedef __attribute__((ext_vector_type(4))) float f32x4;

#define B_ROWS 8192
#define HID 512
#define GATE3 1536
#define ATOM 64
#define NSTEP 49

#define GLOAD_LDS16(gp, sp)                                                   \
  __builtin_amdgcn_global_load_lds(                                           \
      (__attribute__((address_space(1))) void*)(gp),                          \
      (__attribute__((address_space(3))) void*)(sp), 16, 0, 0)

__device__ inline float sig_(float x) { return 1.f / (1.f + __expf(-x)); }
__device__ inline float tanh_(float x) { return 2.f / (1.f + __expf(-2.f * x)) - 1.f; }

// ---------------------------------------------------------------------------
// K1: GRU0. gh0 = h0 @ whh0p^T (direct-frag GEMM), gi0 = G0p[p[row]],
// gate update -> h0_new. Grid: 1024 blocks = 128 m-tiles x 8 n-strips.
// Wave w owns 48-col triple t = (blk&7)*4+w over rows m0..m0+64.
// ---------------------------------------------------------------------------
__global__ __launch_bounds__(256) void gru0_step(
    const __bf16* __restrict__ h0b_c, const __bf16* __restrict__ whh0p,
    const float* __restrict__ G0p, const int* __restrict__ p,
    const float* __restrict__ bhh0p,
    const float* __restrict__ h0f_c, float* __restrict__ h0f_n,
    __bf16* __restrict__ h0b_n)
{
    const int tid = threadIdx.x, lane = tid & 63, w = tid >> 6;
    const int u = lane & 15, q = lane >> 4;
    const int m0 = (blockIdx.x >> 3) * 64;
    const int t  = (blockIdx.x & 7) * 4 + w;
    const int j  = t * 16 + u;
    const int qb = t * 48 + u;

    f32x4 acc[4][3] = {};
    const __bf16* Ab = h0b_c + (size_t)(m0 + u) * HID + q * 8;
    const __bf16* Bb = whh0p + (size_t)(t * 48 + u) * HID + q * 8;

    #pragma unroll 4
    for (int kt = 0; kt < 16; ++kt) {
        const int ko = kt * 32;
        bf16x8 af[4], bf[3];
        #pragma unroll
        for (int mf = 0; mf < 4; ++mf)
            af[mf] = *(const bf16x8*)(Ab + (size_t)mf * 16 * HID + ko);
        #pragma unroll
        for (int g = 0; g < 3; ++g)
            bf[g] = *(const bf16x8*)(Bb + (size_t)g * 16 * HID + ko);
        #pragma unroll
        for (int mf = 0; mf < 4; ++mf)
            #pragma unroll
            for (int g = 0; g < 3; ++g)
                acc[mf][g] = __builtin_amdgcn_mfma_f32_16x16x32_bf16(
                    af[mf], bf[g], acc[mf][g], 0, 0, 0);
    }

    const float bhr = bhh0p[qb], bhz = bhh0p[qb + 16], bhn = bhh0p[qb + 32];
    const int rbase = m0 + q * 4;
    #pragma unroll
    for (int mf = 0; mf < 4; ++mf)
        #pragma unroll
        for (int r = 0; r < 4; ++r) {
            const int row = rbase + mf * 16 + r;
            const float* g0 = G0p + (size_t)p[row] * GATE3 + qb;
            const float rr = sig_(g0[0]  + acc[mf][0][r] + bhr);
            const float zz = sig_(g0[16] + acc[mf][1][r] + bhz);
            const float nn = tanh_(g0[32] + rr * (acc[mf][2][r] + bhn));
            const float hp = h0f_c[(size_t)row * HID + j];
            const float hv = (1.f - zz) * nn + zz * hp;
            h0f_n[(size_t)row * HID + j] = hv;
            h0b_n[(size_t)row * HID + j] = (__bf16)hv;
        }
}

// ---------------------------------------------------------------------------
// K2: GRU1 dual-GEMM. gi1 = h0_new @ wih1p^T, gh1 = h1 @ whh1p^T (two
// sequential direct-frag K-loops), fused gate update -> h1_new.
// ---------------------------------------------------------------------------
__global__ __launch_bounds__(256) void gru1_dual(
    const __bf16* __restrict__ h0b_n, const __bf16* __restrict__ wih1p,
    const __bf16* __restrict__ h1b_c, const __bf16* __restrict__ whh1p,
    const float* __restrict__ bih1p, const float* __restrict__ bhh1p,
    const float* __restrict__ h1f_c, float* __restrict__ h1f_n,
    __bf16* __restrict__ h1b_n)
{
    const int tid = threadIdx.x, lane = tid & 63, w = tid >> 6;
    const int u = lane & 15, q = lane >> 4;
    const int m0 = (blockIdx.x >> 3) * 64;
    const int t  = (blockIdx.x & 7) * 4 + w;
    const int j  = t * 16 + u;
    const int qb = t * 48 + u;

    f32x4 acc_i[4][3] = {};
    {
        const __bf16* Ab = h0b_n + (size_t)(m0 + u) * HID + q * 8;
        const __bf16* Bb = wih1p + (size_t)(t * 48 + u) * HID + q * 8;
        #pragma unroll 4
        for (int kt = 0; kt < 16; ++kt) {
            const int ko = kt * 32;
            bf16x8 af[4], bf[3];
            #pragma unroll
            for (int mf = 0; mf < 4; ++mf)
                af[mf] = *(const bf16x8*)(Ab + (size_t)mf * 16 * HID + ko);
            #pragma unroll
            for (int g = 0; g < 3; ++g)
                bf[g] = *(const bf16x8*)(Bb + (size_t)g * 16 * HID + ko);
            #pragma unroll
            for (int mf = 0; mf < 4; ++mf)
                #pragma unroll
                for (int g = 0; g < 3; ++g)
                    acc_i[mf][g] = __builtin_amdgcn_mfma_f32_16x16x32_bf16(
                        af[mf], bf[g], acc_i[mf][g], 0, 0, 0);
        }
    }
    f32x4 acc_h[4][3] = {};
    {
        const __bf16* Ab = h1b_c + (size_t)(m0 + u) * HID + q * 8;
        const __bf16* Bb = whh1p + (size_t)(t * 48 + u) * HID + q * 8;
        #pragma unroll 4
        for (int kt = 0; kt < 16; ++kt) {
            const int ko = kt * 32;
            bf16x8 af[4], bf[3];
            #pragma unroll
            for (int mf = 0; mf < 4; ++mf)
                af[mf] = *(const bf16x8*)(Ab + (size_t)mf * 16 * HID + ko);
            #pragma unroll
            for (int g = 0; g < 3; ++g)
                bf[g] = *(const bf16x8*)(Bb + (size_t)g * 16 * HID + ko);
            #pragma unroll
            for (int mf = 0; mf < 4; ++mf)
                #pragma unroll
                for (int g = 0; g < 3; ++g)
                    acc_h[mf][g] = __builtin_amdgcn_mfma_f32_16x16x32_bf16(
                        af[mf], bf[g], acc_h[mf][g], 0, 0, 0);
        }
    }

    const float bir = bih1p[qb], biz = bih1p[qb + 16], bin = bih1p[qb + 32];
    const float bhr = bhh1p[qb], bhz = bhh1p[qb + 16], bhn = bhh1p[qb + 32];
    const int rbase = m0 + q * 4;
    #pragma unroll
    for (int mf = 0; mf < 4; ++mf)
        #pragma unroll
        for (int r = 0; r < 4; ++r) {
            const int row = rbase + mf * 16 + r;
            const float rr = sig_(acc_i[mf][0][r] + bir + acc_h[mf][0][r] + bhr);
            const float zz = sig_(acc_i[mf][1][r] + biz + acc_h[mf][1][r] + bhz);
            const float nn = tanh_(acc_i[mf][2][r] + bin +
                                   rr * (acc_h[mf][2][r] + bhn));
            const float hp = h1f_c[(size_t)row * HID + j];
            const float hv = (1.f - zz) * nn + zz * hp;
            h1f_n[(size_t)row * HID + j] = hv;
            h1b_n[(size_t)row * HID + j] = (__bf16)hv;
        }
}

// ---------------------------------------------------------------------------
// K3: logits = h1_new @ w_out^T + b_out (direct-frag, N=64), log_softmax +
// argmax. 128 blocks x 64 rows; wave w rows w*16..; cols nf*16+u.
// ---------------------------------------------------------------------------
__global__ __launch_bounds__(256) void out_step(
    const __bf16* __restrict__ h1b, const __bf16* __restrict__ woutb,
    const float* __restrict__ bout, float* __restrict__ y, int* __restrict__ p)
{
    const int tid = threadIdx.x, lane = tid & 63, w = tid >> 6;
    const int u = lane & 15, q = lane >> 4;
    const int m0 = blockIdx.x * 64;

    f32x4 acc[4] = {};
    const __bf16* Ab = h1b + (size_t)(m0 + w * 16 + u) * HID + q * 8;
    const __bf16* Bb = woutb + (size_t)u * HID + q * 8;

    #pragma unroll 4
    for (int kt = 0; kt < 16; ++kt) {
        const int ko = kt * 32;
        const bf16x8 af = *(const bf16x8*)(Ab + ko);
        #pragma unroll
        for (int nf = 0; nf < 4; ++nf) {
            const bf16x8 bf = *(const bf16x8*)(Bb + (size_t)nf * 16 * HID + ko);
            acc[nf] = __builtin_amdgcn_mfma_f32_16x16x32_bf16(af, bf, acc[nf], 0, 0, 0);
        }
    }

    #pragma unroll
    for (int r = 0; r < 4; ++r) {
        const int row = m0 + w * 16 + q * 4 + r;
        float l[4];
        #pragma unroll
        for (int nf = 0; nf < 4; ++nf) l[nf] = acc[nf][r] + bout[nf * 16 + u];

        float mv = l[0]; int mi = u;
        #pragma unroll
        for (int nf = 1; nf < 4; ++nf)
            if (l[nf] > mv) { mv = l[nf]; mi = nf * 16 + u; }
        #pragma unroll
        for (int off = 1; off <= 8; off <<= 1) {
            const float ov = __shfl_xor(mv, off, 64);
            const int   oi = __shfl_xor(mi, off, 64);
            if (ov > mv || (ov == mv && oi < mi)) { mv = ov; mi = oi; }
        }
        float se = 0.f;
        #pragma unroll
        for (int nf = 0; nf < 4; ++nf) se += __expf(l[nf] - mv);
        #pragma unroll
        for (int off = 1; off <= 8; off <<= 1) se += __shfl_xor(se, off, 64);
        const float lse = logf(se);

        #pragma unroll
        for (int nf = 0; nf < 4; ++nf)
            y[(size_t)row * ATOM + nf * 16 + u] = l[nf] - mv - lse;
        if (u == 0) p[row] = mi;
    }
}

// ---------------------------------------------------------------------------
// Init GEMM (enc -> h): 128x128 tile, LDS-staged (one-time, known-good).
// ---------------------------------------------------------------------------
__global__ __launch_bounds__(256) void gemm_init(
    const __bf16* __restrict__ A, const __bf16* __restrict__ B,
    int N, int K, const float* __restrict__ bias,
    float* __restrict__ H0f, __bf16* __restrict__ H0b,
    float* __restrict__ H1f, __bf16* __restrict__ H1b)
{
    __shared__ __bf16 As[128 * 32];
    __shared__ __bf16 Bs[128 * 32];

    const int tid  = threadIdx.x;
    const int lane = tid & 63;
    const int w    = tid >> 6;
    const int wm   = w >> 1, wn = w & 1;
    const int m0   = blockIdx.x * 128;
    const int n0   = blockIdx.y * 128;

    f32x4 acc[4][4] = {};

    const int i0 = w * 64 + lane;
    const int i1 = i0 + 256;
    const __bf16* Ap0 = A + (size_t)(m0 + (i0 >> 2)) * K + (i0 & 3) * 8;
    const __bf16* Ap1 = A + (size_t)(m0 + (i1 >> 2)) * K + (i1 & 3) * 8;
    const __bf16* Bp0 = B + (size_t)(n0 + (i0 >> 2)) * K + (i0 & 3) * 8;
    const __bf16* Bp1 = B + (size_t)(n0 + (i1 >> 2)) * K + (i1 & 3) * 8;
    __bf16* As0 = As + w * 512;
    __bf16* As1 = As + 2048 + w * 512;
    __bf16* Bs0 = Bs + w * 512;
    __bf16* Bs1 = Bs + 2048 + w * 512;

    const int mrow = wm * 64 + (lane & 15);
    const int nrow = wn * 64 + (lane & 15);
    const int koff = (lane >> 4) * 8;

    for (int kt = 0; kt < K / 32; ++kt) {
        __syncthreads();
        GLOAD_LDS16(Ap0, As0);
        GLOAD_LDS16(Ap1, As1);
        GLOAD_LDS16(Bp0, Bs0);
        GLOAD_LDS16(Bp1, Bs1);
        Ap0 += 32; Ap1 += 32; Bp0 += 32; Bp1 += 32;
        __syncthreads();

        bf16x8 af[4], bfr[4];
        #pragma unroll
        for (int f = 0; f < 4; ++f) {
            af[f]  = *(const bf16x8*)&As[(mrow + f * 16) * 32 + koff];
            bfr[f] = *(const bf16x8*)&Bs[(nrow + f * 16) * 32 + koff];
        }
        #pragma unroll
        for (int mf = 0; mf < 4; ++mf)
            #pragma unroll
            for (int nf = 0; nf < 4; ++nf)
                acc[mf][nf] = __builtin_amdgcn_mfma_f32_16x16x32_bf16(
                    af[mf], bfr[nf], acc[mf][nf], 0, 0, 0);
    }

    const int colb = n0 + wn * 64 + (lane & 15);
    const int rowb = m0 + wm * 64 + ((lane >> 4) << 2);
    #pragma unroll
    for (int mf = 0; mf < 4; ++mf)
        #pragma unroll
        for (int nf = 0; nf < 4; ++nf) {
            const int col = colb + nf * 16;
            #pragma unroll
            for (int r = 0; r < 4; ++r) {
                const int row = rowb + mf * 16 + r;
                const float v = tanhf(acc[mf][nf][r] + bias[col]);
                if (col < HID) {
                    H0f[(size_t)row * HID + col] = v;
                    H0b[(size_t)row * HID + col] = (__bf16)v;
                } else {
                    H1f[(size_t)row * HID + col - HID] = v;
                    H1b[(size_t)row * HID + col - HID] = (__bf16)v;
                }
            }
        }
}

// ---------------------------------------------------------------------------
// prep kernels
// ---------------------------------------------------------------------------
__device__ inline int permQ(int q) {          // permuted q -> original row
    const int t = q / 48, rem = q % 48;
    return (rem / 16) * HID + t * 16 + (rem % 16);
}

__global__ __launch_bounds__(256) void f2b(const float* __restrict__ s,
                                           __bf16* __restrict__ d, int n)
{
    const int i = (blockIdx.x * 256 + threadIdx.x) * 4;
    if (i + 3 < n) {
        const float4 v = *(const float4*)(s + i);
        bf16x4 o = { (__bf16)v.x, (__bf16)v.y, (__bf16)v.z, (__bf16)v.w };
        *(bf16x4*)(d + i) = o;
    }
}

__global__ __launch_bounds__(256) void f2bp(const float* __restrict__ s,
                                            __bf16* __restrict__ d)
{
    const int idx = blockIdx.x * 256 + threadIdx.x;   // 1536*128
    const int q = idx >> 7, k = (idx & 127) << 2;
    const int o = permQ(q);
    const float4 v = *(const float4*)(s + (size_t)o * HID + k);
    bf16x4 ov = { (__bf16)v.x, (__bf16)v.y, (__bf16)v.z, (__bf16)v.w };
    *(bf16x4*)(d + (size_t)q * HID + k) = ov;
}

__global__ __launch_bounds__(256) void bperm(const float* __restrict__ s,
                                             float* __restrict__ d)
{
    const int q = blockIdx.x * 256 + threadIdx.x;
    if (q < GATE3) d[q] = s[permQ(q)];
}

__global__ __launch_bounds__(256) void g0pk(const float* __restrict__ emb,
                                            const float* __restrict__ wih0,
                                            const float* __restrict__ bih0,
                                            float* __restrict__ G0p)
{
    const int i = blockIdx.x * 256 + threadIdx.x;   // 64*1536
    if (i >= ATOM * GATE3) return;
    const int a = i / GATE3, q = i % GATE3;
    const int o = permQ(q);
    float s = bih0[o];
    for (int k = 0; k < 50; ++k) s += emb[a * 50 + k] * wih0[o * 50 + k];
    G0p[i] = s;
}

__global__ __launch_bounds__(256) void initp(int* __restrict__ p)
{
    const int i = blockIdx.x * 256 + threadIdx.x;
    if (i < B_ROWS) p[i] = 1;   // SOS
}

// ---------------------------------------------------------------------------
extern "C" void kernel_launch(void* const* d_in, const int* in_sizes, int n_in,
                              void* d_out, int out_size, void* d_ws, size_t ws_size,
                              hipStream_t stream)
{
    (void)in_sizes; (void)n_in; (void)out_size; (void)ws_size;
    const float* enc   = (const float*)d_in[0];
    const float* emb   = (const float*)d_in[1];
    const float* w_h0  = (const float*)d_in[2];
    const float* b_h0  = (const float*)d_in[3];
    const float* w_ih0 = (const float*)d_in[4];
    const float* w_hh0 = (const float*)d_in[5];
    const float* b_ih0 = (const float*)d_in[6];
    const float* b_hh0 = (const float*)d_in[7];
    const float* w_ih1 = (const float*)d_in[8];
    const float* w_hh1 = (const float*)d_in[9];
    const float* b_ih1 = (const float*)d_in[10];
    const float* b_hh1 = (const float*)d_in[11];
    const float* w_out = (const float*)d_in[12];
    const float* b_out = (const float*)d_in[13];
    float* out = (float*)d_out;

    char* ws = (char*)d_ws;
    size_t off = 0;
    auto alloc = [&](size_t bytes) -> void* {
        void* pp = ws + off;
        off = (off + bytes + 255) & ~(size_t)255;
        return pp;
    };
    __bf16* whh0p = (__bf16*)alloc((size_t)GATE3 * HID * 2);
    __bf16* wih1p = (__bf16*)alloc((size_t)GATE3 * HID * 2);
    __bf16* whh1p = (__bf16*)alloc((size_t)GATE3 * HID * 2);
    __bf16* woutb = (__bf16*)alloc((size_t)ATOM * HID * 2);
    float*  G0p   = (float*) alloc((size_t)ATOM * GATE3 * 4);
    float*  bhh0p = (float*) alloc(GATE3 * 4);
    float*  bih1p = (float*) alloc(GATE3 * 4);
    float*  bhh1p = (float*) alloc(GATE3 * 4);
    float*  h0f[2]; __bf16* h0b[2]; float* h1f[2]; __bf16* h1b[2];
    for (int i = 0; i < 2; ++i) {
        h0f[i] = (float*) alloc((size_t)B_ROWS * HID * 4);
        h0b[i] = (__bf16*)alloc((size_t)B_ROWS * HID * 2);
        h1f[i] = (float*) alloc((size_t)B_ROWS * HID * 4);
        h1b[i] = (__bf16*)alloc((size_t)B_ROWS * HID * 2);
    }
    int* p = (int*)alloc((size_t)B_ROWS * 4);
    __bf16* enc_b = (__bf16*)alloc((size_t)B_ROWS * 1024 * 2);
    __bf16* wh0b  = (__bf16*)alloc((size_t)1024 * 1024 * 2);

    // ---- prep ----
    f2b <<<8192, 256, 0, stream>>>(enc,  enc_b, B_ROWS * 1024);
    f2b <<<1024, 256, 0, stream>>>(w_h0, wh0b,  1024 * 1024);
    f2b <<<32,   256, 0, stream>>>(w_out, woutb, ATOM * HID);
    f2bp<<<768,  256, 0, stream>>>(w_hh0, whh0p);
    f2bp<<<768,  256, 0, stream>>>(w_ih1, wih1p);
    f2bp<<<768,  256, 0, stream>>>(w_hh1, whh1p);
    bperm<<<6, 256, 0, stream>>>(b_hh0, bhh0p);
    bperm<<<6, 256, 0, stream>>>(b_ih1, bih1p);
    bperm<<<6, 256, 0, stream>>>(b_hh1, bhh1p);
    g0pk<<<384, 256, 0, stream>>>(emb, w_ih0, b_ih0, G0p);
    initp<<<32, 256, 0, stream>>>(p);

    gemm_init<<<dim3(B_ROWS / 128, 1024 / 128), 256, 0, stream>>>(
        enc_b, wh0b, 1024, 1024, b_h0, h0f[0], h0b[0], h1f[0], h1b[0]);

    // ---- 49 decode steps: 3 launches each ----
    for (int step = 0; step < NSTEP; ++step) {
        const int cur = step & 1, nxt = cur ^ 1;
        gru0_step<<<1024, 256, 0, stream>>>(
            h0b[cur], whh0p, G0p, p, bhh0p, h0f[cur], h0f[nxt], h0b[nxt]);
        gru1_dual<<<1024, 256, 0, stream>>>(
            h0b[nxt], wih1p, h1b[cur], whh1p, bih1p, bhh1p,
            h1f[cur], h1f[nxt], h1b[nxt]);
        out_step<<<128, 256, 0, stream>>>(
            h1b[nxt], woutb, b_out, out + (size_t)step * B_ROWS * ATOM, p);
    }
}

// Round 5
// 4699.902 us; speedup vs baseline: 5.1906x; 2.0327x over previous
//
#include <hip/hip_runtime.h>
#include <hip/hip_bf16.h>
#include <cstdint>
#include <cstddef>

// ---------------------------------------------------------------------------
// 2-layer GRU decoder. B=8192, H=512, ENC=1024, ATOM=64, 49 steps.
// 3 kernels/step: gru0_step (LDS GEMM + gate), gru1_dual (2 LDS GEMMs +
// gate), out_mfma (logits+log_softmax+argmax).
// Gate-permuted weights: q = 48*(j/16) + 16*g + (j%16) <-> orig row g*512+j,
// so a 48-col wave strip holds gates r,z,n for 16 h-units at matching lanes.
// Grid dim3(128,8): m-tile fastest-varying => consecutive blocks round-robin
// across XCDs get consecutive m-tiles of ONE strip; each XCD only reads
// m-tiles === xcd (mod 8)  (R4 post-mortem: wrong order => 8x HBM fetch).
// ---------------------------------------------------------------------------

typedef __attribute__((ext_vector_type(8))) __bf16 bf16x8;
typedef __attribute__((ext_vector_type(4))) __bf16 bf16x4;
typedef __attribute__((ext_vector_type(4))) float f32x4;

#define B_ROWS 8192
#define HID 512
#define GATE3 1536
#define ATOM 64
#define NSTEP 49

#define GLOAD_LDS16(gp, sp)                                                   \
  __builtin_amdgcn_global_load_lds(                                           \
      (__attribute__((address_space(1))) void*)(gp),                          \
      (__attribute__((address_space(3))) void*)(sp), 16, 0, 0)

__device__ inline float sig_(float x) { return 1.f / (1.f + __expf(-x)); }
__device__ inline float tanh_(float x) { return 2.f / (1.f + __expf(-2.f * x)) - 1.f; }

// ---------------------------------------------------------------------------
// Core tile GEMM: acc += A[m0..+64) @ Bp[n0..+192)^T, K=512, BK=32.
// 4 waves: wave w owns the 48-col triple (w*48) within the 192-col strip.
// ---------------------------------------------------------------------------
__device__ __forceinline__ void gru_mm(
    const __bf16* __restrict__ A, const __bf16* __restrict__ Bp,
    int m0, int n0, int tid, __bf16* As, __bf16* Bs, f32x4 (&acc)[4][3])
{
    const int lane = tid & 63, w = tid >> 6;
    const int u = lane & 15, koff = (lane >> 4) * 8;
    const __bf16* Ap  = A  + (size_t)(m0 + (tid >> 2)) * HID + (tid & 3) * 8;
    const __bf16* Bg0 = Bp + (size_t)(n0 + (tid >> 2)) * HID + (tid & 3) * 8;
    const __bf16* Bg1 = Bg0 + (size_t)64  * HID;
    const __bf16* Bg2 = Bg0 + (size_t)128 * HID;
    __bf16* AsW  = As + w * 512;
    __bf16* BsW0 = Bs + w * 512;
    __bf16* BsW1 = Bs + 2048 + w * 512;
    __bf16* BsW2 = Bs + 4096 + w * 512;

    for (int kt = 0; kt < HID / 32; ++kt) {
        __syncthreads();
        GLOAD_LDS16(Ap,  AsW);
        GLOAD_LDS16(Bg0, BsW0);
        GLOAD_LDS16(Bg1, BsW1);
        GLOAD_LDS16(Bg2, BsW2);
        Ap += 32; Bg0 += 32; Bg1 += 32; Bg2 += 32;
        __syncthreads();

        bf16x8 af[4], bfr[3];
        #pragma unroll
        for (int mf = 0; mf < 4; ++mf)
            af[mf] = *(const bf16x8*)&As[(mf * 16 + u) * 32 + koff];
        #pragma unroll
        for (int g = 0; g < 3; ++g)
            bfr[g] = *(const bf16x8*)&Bs[(w * 48 + g * 16 + u) * 32 + koff];
        #pragma unroll
        for (int mf = 0; mf < 4; ++mf)
            #pragma unroll
            for (int g = 0; g < 3; ++g)
                acc[mf][g] = __builtin_amdgcn_mfma_f32_16x16x32_bf16(
                    af[mf], bfr[g], acc[mf][g], 0, 0, 0);
    }
}

// ---------------------------------------------------------------------------
// K1: GRU0. gh0 = h0 @ whh0p^T; gi0 = G0p[p[row]] (b_ih0 folded);
// gate update -> h0_new (fp32 + bf16 mirror).
// ---------------------------------------------------------------------------
__global__ __launch_bounds__(256) void gru0_step(
    const __bf16* __restrict__ h0b_c, const __bf16* __restrict__ whh0p,
    const float* __restrict__ G0p, const int* __restrict__ p,
    const float* __restrict__ bhh0p,
    const float* __restrict__ h0f_c, float* __restrict__ h0f_n,
    __bf16* __restrict__ h0b_n)
{
    __shared__ __bf16 As[64 * 32];    // 4 KB
    __shared__ __bf16 Bs[192 * 32];   // 12 KB

    const int tid = threadIdx.x, lane = tid & 63, w = tid >> 6;
    const int u = lane & 15;
    const int m0 = blockIdx.x * 64;
    const int n0 = blockIdx.y * 192;
    const int t  = blockIdx.y * 4 + w;
    const int j  = t * 16 + u;
    const int qb = t * 48 + u;

    f32x4 acc[4][3] = {};
    gru_mm(h0b_c, whh0p, m0, n0, tid, As, Bs, acc);

    const float bhr = bhh0p[qb], bhz = bhh0p[qb + 16], bhn = bhh0p[qb + 32];
    const int rbase = m0 + ((lane >> 4) << 2);
    #pragma unroll
    for (int mf = 0; mf < 4; ++mf)
        #pragma unroll
        for (int r = 0; r < 4; ++r) {
            const int row = rbase + mf * 16 + r;
            const float* g0 = G0p + (size_t)p[row] * GATE3 + qb;
            const float rr = sig_(g0[0]  + acc[mf][0][r] + bhr);
            const float zz = sig_(g0[16] + acc[mf][1][r] + bhz);
            const float nn = tanh_(g0[32] + rr * (acc[mf][2][r] + bhn));
            const float hp = h0f_c[(size_t)row * HID + j];
            const float hv = (1.f - zz) * nn + zz * hp;
            h0f_n[(size_t)row * HID + j] = hv;
            h0b_n[(size_t)row * HID + j] = (__bf16)hv;
        }
}

// ---------------------------------------------------------------------------
// K2: GRU1 dual. gi1 = h0_new @ wih1p^T, gh1 = h1 @ whh1p^T (two sequential
// LDS K-loops, same LDS), fused gate update -> h1_new. gi1 never rounded.
// ---------------------------------------------------------------------------
__global__ __launch_bounds__(256) void gru1_dual(
    const __bf16* __restrict__ h0b_n, const __bf16* __restrict__ wih1p,
    const __bf16* __restrict__ h1b_c, const __bf16* __restrict__ whh1p,
    const float* __restrict__ bih1p, const float* __restrict__ bhh1p,
    const float* __restrict__ h1f_c, float* __restrict__ h1f_n,
    __bf16* __restrict__ h1b_n)
{
    __shared__ __bf16 As[64 * 32];
    __shared__ __bf16 Bs[192 * 32];

    const int tid = threadIdx.x, lane = tid & 63, w = tid >> 6;
    const int u = lane & 15;
    const int m0 = blockIdx.x * 64;
    const int n0 = blockIdx.y * 192;
    const int t  = blockIdx.y * 4 + w;
    const int j  = t * 16 + u;
    const int qb = t * 48 + u;

    f32x4 acc_i[4][3] = {};
    gru_mm(h0b_n, wih1p, m0, n0, tid, As, Bs, acc_i);
    f32x4 acc_h[4][3] = {};
    gru_mm(h1b_c, whh1p, m0, n0, tid, As, Bs, acc_h);

    const float bir = bih1p[qb], biz = bih1p[qb + 16], bin = bih1p[qb + 32];
    const float bhr = bhh1p[qb], bhz = bhh1p[qb + 16], bhn = bhh1p[qb + 32];
    const int rbase = m0 + ((lane >> 4) << 2);
    #pragma unroll
    for (int mf = 0; mf < 4; ++mf)
        #pragma unroll
        for (int r = 0; r < 4; ++r) {
            const int row = rbase + mf * 16 + r;
            const float rr = sig_(acc_i[mf][0][r] + bir + acc_h[mf][0][r] + bhr);
            const float zz = sig_(acc_i[mf][1][r] + biz + acc_h[mf][1][r] + bhz);
            const float nn = tanh_(acc_i[mf][2][r] + bin +
                                   rr * (acc_h[mf][2][r] + bhn));
            const float hp = h1f_c[(size_t)row * HID + j];
            const float hv = (1.f - zz) * nn + zz * hp;
            h1f_n[(size_t)row * HID + j] = hv;
            h1b_n[(size_t)row * HID + j] = (__bf16)hv;
        }
}

// ---------------------------------------------------------------------------
// K3: logits = h1_new @ w_out^T + b_out (MFMA, BM=64, N=64, K=512);
// log_softmax + argmax fused. 128 blocks; wave w -> rows w*16..; cols nf*16+u.
// ---------------------------------------------------------------------------
__global__ __launch_bounds__(256) void out_mfma(
    const __bf16* __restrict__ h1b, const __bf16* __restrict__ woutb,
    const float* __restrict__ bout, float* __restrict__ y, int* __restrict__ p)
{
    __shared__ __bf16 As[64 * 32];
    __shared__ __bf16 Bs[64 * 32];

    const int tid  = threadIdx.x;
    const int lane = tid & 63;
    const int w    = tid >> 6;
    const int m0   = blockIdx.x * 64;

    f32x4 acc[4] = {};

    const __bf16* Ap = h1b   + (size_t)(m0 + (tid >> 2)) * HID + (tid & 3) * 8;
    const __bf16* Wp = woutb + (size_t)(tid >> 2) * HID + (tid & 3) * 8;
    __bf16* AsW = As + w * 512;
    __bf16* BsW = Bs + w * 512;

    const int u    = lane & 15;
    const int koff = (lane >> 4) * 8;

    for (int kt = 0; kt < HID / 32; ++kt) {
        __syncthreads();
        GLOAD_LDS16(Ap, AsW);
        GLOAD_LDS16(Wp, BsW);
        Ap += 32; Wp += 32;
        __syncthreads();

        const bf16x8 af = *(const bf16x8*)&As[(w * 16 + u) * 32 + koff];
        #pragma unroll
        for (int nf = 0; nf < 4; ++nf) {
            const bf16x8 bfr = *(const bf16x8*)&Bs[(nf * 16 + u) * 32 + koff];
            acc[nf] = __builtin_amdgcn_mfma_f32_16x16x32_bf16(af, bfr, acc[nf], 0, 0, 0);
        }
    }

    #pragma unroll
    for (int r = 0; r < 4; ++r) {
        const int row = m0 + w * 16 + ((lane >> 4) << 2) + r;
        float l[4];
        #pragma unroll
        for (int nf = 0; nf < 4; ++nf) l[nf] = acc[nf][r] + bout[nf * 16 + u];

        float mv = l[0]; int mi = u;
        #pragma unroll
        for (int nf = 1; nf < 4; ++nf)
            if (l[nf] > mv) { mv = l[nf]; mi = nf * 16 + u; }
        #pragma unroll
        for (int off = 1; off <= 8; off <<= 1) {
            const float ov = __shfl_xor(mv, off, 64);
            const int   oi = __shfl_xor(mi, off, 64);
            if (ov > mv || (ov == mv && oi < mi)) { mv = ov; mi = oi; }
        }
        float se = 0.f;
        #pragma unroll
        for (int nf = 0; nf < 4; ++nf) se += __expf(l[nf] - mv);
        #pragma unroll
        for (int off = 1; off <= 8; off <<= 1) se += __shfl_xor(se, off, 64);
        const float lse = logf(se);

        #pragma unroll
        for (int nf = 0; nf < 4; ++nf)
            y[(size_t)row * ATOM + nf * 16 + u] = l[nf] - mv - lse;
        if (u == 0) p[row] = mi;
    }
}

// ---------------------------------------------------------------------------
// Init GEMM (enc -> h): 128x128 tile, LDS-staged, tanh epilogue split h0|h1.
// ---------------------------------------------------------------------------
__global__ __launch_bounds__(256) void gemm_init(
    const __bf16* __restrict__ A, const __bf16* __restrict__ B,
    int N, int K, const float* __restrict__ bias,
    float* __restrict__ H0f, __bf16* __restrict__ H0b,
    float* __restrict__ H1f, __bf16* __restrict__ H1b)
{
    __shared__ __bf16 As[128 * 32];
    __shared__ __bf16 Bs[128 * 32];

    const int tid  = threadIdx.x;
    const int lane = tid & 63;
    const int w    = tid >> 6;
    const int wm   = w >> 1, wn = w & 1;
    const int m0   = blockIdx.x * 128;
    const int n0   = blockIdx.y * 128;

    f32x4 acc[4][4] = {};

    const int i0 = w * 64 + lane;
    const int i1 = i0 + 256;
    const __bf16* Ap0 = A + (size_t)(m0 + (i0 >> 2)) * K + (i0 & 3) * 8;
    const __bf16* Ap1 = A + (size_t)(m0 + (i1 >> 2)) * K + (i1 & 3) * 8;
    const __bf16* Bp0 = B + (size_t)(n0 + (i0 >> 2)) * K + (i0 & 3) * 8;
    const __bf16* Bp1 = B + (size_t)(n0 + (i1 >> 2)) * K + (i1 & 3) * 8;
    __bf16* As0 = As + w * 512;
    __bf16* As1 = As + 2048 + w * 512;
    __bf16* Bs0 = Bs + w * 512;
    __bf16* Bs1 = Bs + 2048 + w * 512;

    const int mrow = wm * 64 + (lane & 15);
    const int nrow = wn * 64 + (lane & 15);
    const int koff = (lane >> 4) * 8;

    for (int kt = 0; kt < K / 32; ++kt) {
        __syncthreads();
        GLOAD_LDS16(Ap0, As0);
        GLOAD_LDS16(Ap1, As1);
        GLOAD_LDS16(Bp0, Bs0);
        GLOAD_LDS16(Bp1, Bs1);
        Ap0 += 32; Ap1 += 32; Bp0 += 32; Bp1 += 32;
        __syncthreads();

        bf16x8 af[4], bfr[4];
        #pragma unroll
        for (int f = 0; f < 4; ++f) {
            af[f]  = *(const bf16x8*)&As[(mrow + f * 16) * 32 + koff];
            bfr[f] = *(const bf16x8*)&Bs[(nrow + f * 16) * 32 + koff];
        }
        #pragma unroll
        for (int mf = 0; mf < 4; ++mf)
            #pragma unroll
            for (int nf = 0; nf < 4; ++nf)
                acc[mf][nf] = __builtin_amdgcn_mfma_f32_16x16x32_bf16(
                    af[mf], bfr[nf], acc[mf][nf], 0, 0, 0);
    }

    const int colb = n0 + wn * 64 + (lane & 15);
    const int rowb = m0 + wm * 64 + ((lane >> 4) << 2);
    #pragma unroll
    for (int mf = 0; mf < 4; ++mf)
        #pragma unroll
        for (int nf = 0; nf < 4; ++nf) {
            const int col = colb + nf * 16;
            #pragma unroll
            for (int r = 0; r < 4; ++r) {
                const int row = rowb + mf * 16 + r;
                const float v = tanhf(acc[mf][nf][r] + bias[col]);
                if (col < HID) {
                    H0f[(size_t)row * HID + col] = v;
                    H0b[(size_t)row * HID + col] = (__bf16)v;
                } else {
                    H1f[(size_t)row * HID + col - HID] = v;
                    H1b[(size_t)row * HID + col - HID] = (__bf16)v;
                }
            }
        }
}

// ---------------------------------------------------------------------------
// prep kernels
// ---------------------------------------------------------------------------
__device__ inline int permQ(int q) {          // permuted q -> original row
    const int t = q / 48, rem = q % 48;
    return (rem / 16) * HID + t * 16 + (rem % 16);
}

__global__ __launch_bounds__(256) void f2b(const float* __restrict__ s,
                                           __bf16* __restrict__ d, int n)
{
    const int i = (blockIdx.x * 256 + threadIdx.x) * 4;
    if (i + 3 < n) {
        const float4 v = *(const float4*)(s + i);
        bf16x4 o = { (__bf16)v.x, (__bf16)v.y, (__bf16)v.z, (__bf16)v.w };
        *(bf16x4*)(d + i) = o;
    }
}

__global__ __launch_bounds__(256) void f2bp(const float* __restrict__ s,
                                            __bf16* __restrict__ d)
{
    const int idx = blockIdx.x * 256 + threadIdx.x;   // 1536*128
    const int q = idx >> 7, k = (idx & 127) << 2;
    const int o = permQ(q);
    const float4 v = *(const float4*)(s + (size_t)o * HID + k);
    bf16x4 ov = { (__bf16)v.x, (__bf16)v.y, (__bf16)v.z, (__bf16)v.w };
    *(bf16x4*)(d + (size_t)q * HID + k) = ov;
}

__global__ __launch_bounds__(256) void bperm(const float* __restrict__ s,
                                             float* __restrict__ d)
{
    const int q = blockIdx.x * 256 + threadIdx.x;
    if (q < GATE3) d[q] = s[permQ(q)];
}

__global__ __launch_bounds__(256) void g0pk(const float* __restrict__ emb,
                                            const float* __restrict__ wih0,
                                            const float* __restrict__ bih0,
                                            float* __restrict__ G0p)
{
    const int i = blockIdx.x * 256 + threadIdx.x;   // 64*1536
    if (i >= ATOM * GATE3) return;
    const int a = i / GATE3, q = i % GATE3;
    const int o = permQ(q);
    float s = bih0[o];
    for (int k = 0; k < 50; ++k) s += emb[a * 50 + k] * wih0[o * 50 + k];
    G0p[i] = s;
}

__global__ __launch_bounds__(256) void initp(int* __restrict__ p)
{
    const int i = blockIdx.x * 256 + threadIdx.x;
    if (i < B_ROWS) p[i] = 1;   // SOS
}

// ---------------------------------------------------------------------------
extern "C" void kernel_launch(void* const* d_in, const int* in_sizes, int n_in,
                              void* d_out, int out_size, void* d_ws, size_t ws_size,
                              hipStream_t stream)
{
    (void)in_sizes; (void)n_in; (void)out_size; (void)ws_size;
    const float* enc   = (const float*)d_in[0];
    const float* emb   = (const float*)d_in[1];
    const float* w_h0  = (const float*)d_in[2];
    const float* b_h0  = (const float*)d_in[3];
    const float* w_ih0 = (const float*)d_in[4];
    const float* w_hh0 = (const float*)d_in[5];
    const float* b_ih0 = (const float*)d_in[6];
    const float* b_hh0 = (const float*)d_in[7];
    const float* w_ih1 = (const float*)d_in[8];
    const float* w_hh1 = (const float*)d_in[9];
    const float* b_ih1 = (const float*)d_in[10];
    const float* b_hh1 = (const float*)d_in[11];
    const float* w_out = (const float*)d_in[12];
    const float* b_out = (const float*)d_in[13];
    float* out = (float*)d_out;

    char* ws = (char*)d_ws;
    size_t off = 0;
    auto alloc = [&](size_t bytes) -> void* {
        void* pp = ws + off;
        off = (off + bytes + 255) & ~(size_t)255;
        return pp;
    };
    __bf16* whh0p = (__bf16*)alloc((size_t)GATE3 * HID * 2);
    __bf16* wih1p = (__bf16*)alloc((size_t)GATE3 * HID * 2);
    __bf16* whh1p = (__bf16*)alloc((size_t)GATE3 * HID * 2);
    __bf16* woutb = (__bf16*)alloc((size_t)ATOM * HID * 2);
    float*  G0p   = (float*) alloc((size_t)ATOM * GATE3 * 4);
    float*  bhh0p = (float*) alloc(GATE3 * 4);
    float*  bih1p = (float*) alloc(GATE3 * 4);
    float*  bhh1p = (float*) alloc(GATE3 * 4);
    float*  h0f[2]; __bf16* h0b[2]; float* h1f[2]; __bf16* h1b[2];
    for (int i = 0; i < 2; ++i) {
        h0f[i] = (float*) alloc((size_t)B_ROWS * HID * 4);
        h0b[i] = (__bf16*)alloc((size_t)B_ROWS * HID * 2);
        h1f[i] = (float*) alloc((size_t)B_ROWS * HID * 4);
        h1b[i] = (__bf16*)alloc((size_t)B_ROWS * HID * 2);
    }
    int* p = (int*)alloc((size_t)B_ROWS * 4);
    __bf16* enc_b = (__bf16*)alloc((size_t)B_ROWS * 1024 * 2);
    __bf16* wh0b  = (__bf16*)alloc((size_t)1024 * 1024 * 2);

    // ---- prep ----
    f2b <<<8192, 256, 0, stream>>>(enc,  enc_b, B_ROWS * 1024);
    f2b <<<1024, 256, 0, stream>>>(w_h0, wh0b,  1024 * 1024);
    f2b <<<32,   256, 0, stream>>>(w_out, woutb, ATOM * HID);
    f2bp<<<768,  256, 0, stream>>>(w_hh0, whh0p);
    f2bp<<<768,  256, 0, stream>>>(w_ih1, wih1p);
    f2bp<<<768,  256, 0, stream>>>(w_hh1, whh1p);
    bperm<<<6, 256, 0, stream>>>(b_hh0, bhh0p);
    bperm<<<6, 256, 0, stream>>>(b_ih1, bih1p);
    bperm<<<6, 256, 0, stream>>>(b_hh1, bhh1p);
    g0pk<<<384, 256, 0, stream>>>(emb, w_ih0, b_ih0, G0p);
    initp<<<32, 256, 0, stream>>>(p);

    gemm_init<<<dim3(B_ROWS / 128, 1024 / 128), 256, 0, stream>>>(
        enc_b, wh0b, 1024, 1024, b_h0, h0f[0], h0b[0], h1f[0], h1b[0]);

    // ---- 49 decode steps: 3 launches each ----
    const dim3 gGrid(B_ROWS / 64, GATE3 / 192);   // m-tile fastest (XCD locality)
    for (int step = 0; step < NSTEP; ++step) {
        const int cur = step & 1, nxt = cur ^ 1;
        gru0_step<<<gGrid, 256, 0, stream>>>(
            h0b[cur], whh0p, G0p, p, bhh0p, h0f[cur], h0f[nxt], h0b[nxt]);
        gru1_dual<<<gGrid, 256, 0, stream>>>(
            h0b[nxt], wih1p, h1b[cur], whh1p, bih1p, bhh1p,
            h1f[cur], h1f[nxt], h1b[nxt]);
        out_mfma<<<B_ROWS / 64, 256, 0, stream>>>(
            h1b[nxt], woutb, b_out, out + (size_t)step * B_ROWS * ATOM, p);
    }
}